// Round 5
// baseline (375.164 us; speedup 1.0000x reference)
//
#include <hip/hip_runtime.h>
#include <math.h>

typedef __bf16 bf16;
typedef __attribute__((ext_vector_type(8))) __bf16 bf16x8;
typedef __attribute__((ext_vector_type(4))) float f32x4;

#define NHEADS 12
#define HDIM 64
#define BATCH 4
#define SEQ 2048
#define CDIM 768
#define MTOK (BATCH * SEQ)                    // 8192 tokens
#define PERPART ((size_t)MTOK * CDIM)         // 6291456 elems per Q/K/V part

// ---------------------------------------------------------------------------
// GEMM: C[M x NCOLS] = A[M x 768] * W[768 x NCOLS], 64x64 tile, BK=32,
// 256 threads = 4 waves; wave w owns cols [w*16,+16), 4 m-tiles of 16.
// Inputs fp32 (reference dtypes); LDS tiles bf16; MFMA accumulates fp32.
// MODE 0: A = fp32 x;  epilogue scatters bf16 q/k/v [b,h,n,d] into ws
// MODE 1: A = bf16 attn-out from ws; epilogue += bias, fp32 out [8192,768]
// ---------------------------------------------------------------------------
template<int NCOLS, int MODE>
__global__ __launch_bounds__(256)
void gemm_kernel(const void* __restrict__ Ap, const float* __restrict__ W,
                 const float* __restrict__ bias, bf16* __restrict__ outb,
                 float* __restrict__ outf)
{
    // pad to 40 elems (80B, 16B-aligned rows): frag reads land 2-way (free)
    __shared__ bf16 As[64][40];   // As[m][k]
    __shared__ bf16 Bs[64][40];   // Bs[n][k] (W transposed), k XOR-swizzled per n

    const int t    = threadIdx.x;
    const int wv   = t >> 6;
    const int lane = t & 63;
    const int ln   = lane & 15;
    const int quad = lane >> 4;
    const int m0   = blockIdx.x * 64;
    const int n0   = blockIdx.y * 64;

    f32x4 acc[4] = {};            // acc[mt]: rows mt*16+quad*4+r, col wv*16+ln

    const int arow = t >> 2, acg = t & 3;   // A staging: row, 8-elem chunk
    const int bk   = t >> 3, bng = t & 7;   // B staging: k-row, 8-col group

    for (int k0 = 0; k0 < CDIM; k0 += 32) {
        // stage A tile
        if constexpr (MODE == 0) {
            const float* A = (const float*)Ap;             // fp32 input x
            const float* src = A + (size_t)(m0 + arow) * CDIM + k0 + acg * 8;
            alignas(16) bf16 tb[8];
            #pragma unroll
            for (int e = 0; e < 8; ++e) tb[e] = (bf16)src[e];
            *(uint4*)&As[arow][acg * 8] = *(const uint4*)tb;
        } else {
            const bf16* A = (const bf16*)Ap;               // bf16 attn output
            *(uint4*)&As[arow][acg * 8] =
                *(const uint4*)(A + (size_t)(m0 + arow) * CDIM + k0 + acg * 8);
        }
        // stage B tile transposed from fp32 W; swizzle k' = k ^ 8*((n>>3)&3)
        // to break the transpose-write bank conflict down to ~4-way
        {
            const float* src = W + (size_t)(k0 + bk) * NCOLS + n0 + bng * 8;
            const int kx = bk ^ ((bng & 3) * 8);
            #pragma unroll
            for (int e = 0; e < 8; ++e)
                Bs[bng * 8 + e][kx] = (bf16)src[e];
        }
        __syncthreads();
        {
            const int n = wv * 16 + ln;
            const int g = (n >> 3) & 3;
            const bf16x8 bfrag = *(const bf16x8*)&Bs[n][(quad ^ g) * 8];
            #pragma unroll
            for (int mt = 0; mt < 4; ++mt) {
                const bf16x8 afrag = *(const bf16x8*)&As[mt * 16 + ln][quad * 8];
                acc[mt] = __builtin_amdgcn_mfma_f32_16x16x32_bf16(afrag, bfrag, acc[mt], 0, 0, 0);
            }
        }
        __syncthreads();
    }

    const int c = n0 + wv * 16 + ln;   // global output column (fixed per lane)
    if constexpr (MODE == 0) {
        // 64-col tile == exactly one (part p, head h); d = c % 64
        const int p = c / CDIM;
        const int h = (c % CDIM) / HDIM;
        const int d = c % HDIM;
        bf16* dst = outb + (size_t)p * PERPART;
        #pragma unroll
        for (int mt = 0; mt < 4; ++mt) {
            #pragma unroll
            for (int r = 0; r < 4; ++r) {
                const int row = m0 + mt * 16 + quad * 4 + r;   // token index
                const int b = row >> 11, nn = row & 2047;
                dst[((size_t)((b * NHEADS + h) * SEQ + nn)) * HDIM + d] = (bf16)acc[mt][r];
            }
        }
    } else {
        const float bv = bias[c];
        #pragma unroll
        for (int mt = 0; mt < 4; ++mt) {
            #pragma unroll
            for (int r = 0; r < 4; ++r) {
                const int row = m0 + mt * 16 + quad * 4 + r;
                outf[(size_t)row * CDIM + c] = acc[mt][r] + bv;   // fp32 out
            }
        }
    }
}

// ---------------------------------------------------------------------------
// Flash attention: grid (SEQ/64, B*H), 256 threads = 4 waves.
// Wave w owns queries [q0 + w*16, +16). Iterate 64-key blocks with online
// softmax. Scale (1/8) pre-folded into Q (exact in bf16).
// ---------------------------------------------------------------------------
__global__ __launch_bounds__(256)
void attn_kernel(const bf16* __restrict__ Qg, const bf16* __restrict__ Kg,
                 const bf16* __restrict__ Vg, bf16* __restrict__ Og)
{
    // 72-elem rows: 144B (16B-aligned), frag reads 2-way (free)
    __shared__ bf16 Qs[64][72];        // Qs[q][d], scaled
    __shared__ bf16 Ks[64][72];        // Ks[key][d]
    __shared__ bf16 Vt[64][72];        // Vt[d][key], key XOR-swizzled per d
    __shared__ bf16 Ps[4][16][72];     // per-wave P[q_local][key]

    const int t    = threadIdx.x;
    const int wv   = t >> 6;
    const int lane = t & 63;
    const int ln   = lane & 15;
    const int quad = lane >> 4;
    const int bh   = blockIdx.y;
    const int q0   = blockIdx.x * 64;

    const bf16* Qb = Qg + (size_t)bh * SEQ * HDIM;
    const bf16* Kb = Kg + (size_t)bh * SEQ * HDIM;
    const bf16* Vb = Vg + (size_t)bh * SEQ * HDIM;

    const int srow = t >> 2, scg = t & 3;    // staging: row, 16-elem chunk

    // stage Q once (scale folded); first in-loop barrier publishes it
    {
        const bf16* src = Qb + (size_t)(q0 + srow) * HDIM + scg * 16;
        #pragma unroll
        for (int e = 0; e < 16; ++e)
            Qs[srow][scg * 16 + e] = (bf16)((float)src[e] * 0.125f);
    }

    float m_i[4], l_i[4];
    f32x4 o_acc[4] = {};
    #pragma unroll
    for (int r = 0; r < 4; ++r) { m_i[r] = -INFINITY; l_i[r] = 0.0f; }

    for (int kb = 0; kb < SEQ / 64; ++kb) {
        const bf16* Ksrc = Kb + (size_t)kb * 64 * HDIM;
        const bf16* Vsrc = Vb + (size_t)kb * 64 * HDIM;
        // stage K (contiguous)
        {
            const uint4 v0 = *(const uint4*)(Ksrc + (size_t)srow * HDIM + scg * 16);
            const uint4 v1 = *(const uint4*)(Ksrc + (size_t)srow * HDIM + scg * 16 + 8);
            *(uint4*)&Ks[srow][scg * 16]     = v0;
            *(uint4*)&Ks[srow][scg * 16 + 8] = v1;
        }
        // stage V transposed; swizzle key' = key ^ 8*((d>>4)&3)
        {
            alignas(16) bf16 tmp[16];
            *(uint4*)&tmp[0] = *(const uint4*)(Vsrc + (size_t)srow * HDIM + scg * 16);
            *(uint4*)&tmp[8] = *(const uint4*)(Vsrc + (size_t)srow * HDIM + scg * 16 + 8);
            #pragma unroll
            for (int e = 0; e < 16; ++e) {
                const int d = scg * 16 + e;
                Vt[d][srow ^ (((d >> 4) & 3) * 8)] = tmp[e];
            }
        }
        __syncthreads();

        // S = (Q*scale) K^T : s[nt][r] = S[quad*4+r][nt*16+ln]
        f32x4 s[4];
        #pragma unroll
        for (int nt = 0; nt < 4; ++nt) {
            s[nt] = f32x4{0.f, 0.f, 0.f, 0.f};
            #pragma unroll
            for (int kk = 0; kk < 2; ++kk) {
                const bf16x8 af = *(const bf16x8*)&Qs[wv * 16 + ln][kk * 32 + quad * 8];
                const bf16x8 bf_ = *(const bf16x8*)&Ks[nt * 16 + ln][kk * 32 + quad * 8];
                s[nt] = __builtin_amdgcn_mfma_f32_16x16x32_bf16(af, bf_, s[nt], 0, 0, 0);
            }
        }

        // online softmax: rows quad*4+r live in this quad's 16 lanes
        float mnew[4];
        #pragma unroll
        for (int r = 0; r < 4; ++r)
            mnew[r] = fmaxf(fmaxf(s[0][r], s[1][r]), fmaxf(s[2][r], s[3][r]));
        #pragma unroll
        for (int off = 1; off < 16; off <<= 1)
            #pragma unroll
            for (int r = 0; r < 4; ++r)
                mnew[r] = fmaxf(mnew[r], __shfl_xor(mnew[r], off));

        float alpha[4];
        #pragma unroll
        for (int r = 0; r < 4; ++r) {
            const float mn = fmaxf(m_i[r], mnew[r]);
            alpha[r] = __expf(m_i[r] - mn);
            m_i[r] = mn;
        }
        float p[4][4], rs[4];
        #pragma unroll
        for (int r = 0; r < 4; ++r) rs[r] = 0.0f;
        #pragma unroll
        for (int nt = 0; nt < 4; ++nt)
            #pragma unroll
            for (int r = 0; r < 4; ++r) {
                p[nt][r] = __expf(s[nt][r] - m_i[r]);
                rs[r] += p[nt][r];
            }
        #pragma unroll
        for (int off = 1; off < 16; off <<= 1)
            #pragma unroll
            for (int r = 0; r < 4; ++r)
                rs[r] += __shfl_xor(rs[r], off);
        #pragma unroll
        for (int r = 0; r < 4; ++r) l_i[r] = l_i[r] * alpha[r] + rs[r];
        #pragma unroll
        for (int nt = 0; nt < 4; ++nt)
            #pragma unroll
            for (int r = 0; r < 4; ++r)
                o_acc[nt][r] *= alpha[r];

        // P: C/D layout -> LDS -> A layout (per-wave buffer)
        #pragma unroll
        for (int nt = 0; nt < 4; ++nt)
            #pragma unroll
            for (int r = 0; r < 4; ++r)
                Ps[wv][quad * 4 + r][nt * 16 + ln] = (bf16)p[nt][r];
        __syncthreads();

        // O += P V  (B-frag from Vt with matching swizzle)
        #pragma unroll
        for (int nt = 0; nt < 4; ++nt) {
            const int n = nt * 16 + ln;           // output dim
            const int g = (n >> 4) & 3;
            #pragma unroll
            for (int kk = 0; kk < 2; ++kk) {
                const bf16x8 af = *(const bf16x8*)&Ps[wv][ln][kk * 32 + quad * 8];
                const bf16x8 bf_ = *(const bf16x8*)&Vt[n][kk * 32 + (quad ^ g) * 8];
                o_acc[nt] = __builtin_amdgcn_mfma_f32_16x16x32_bf16(af, bf_, o_acc[nt], 0, 0, 0);
            }
        }
        __syncthreads();   // protect Ks/Vt before next staging
    }

    // epilogue: ao[b, n, h, d] row-major [8192, 768] bf16
    const int b = bh / NHEADS, h = bh % NHEADS;
    #pragma unroll
    for (int nt = 0; nt < 4; ++nt) {
        const int d = nt * 16 + ln;
        #pragma unroll
        for (int r = 0; r < 4; ++r) {
            const int q = q0 + wv * 16 + quad * 4 + r;
            Og[((size_t)(b * SEQ + q)) * CDIM + h * HDIM + d] = (bf16)(o_acc[nt][r] / l_i[r]);
        }
    }
}

// ---------------------------------------------------------------------------
extern "C" void kernel_launch(void* const* d_in, const int* in_sizes, int n_in,
                              void* d_out, int out_size, void* d_ws, size_t ws_size,
                              hipStream_t stream)
{
    // dtype model (R5, consistent with all 5 rounds of evidence):
    // inputs fp32, output fp32.
    // Defensive: select input pointers by their unique flat sizes.
    const float* x     = (const float*)d_in[0];
    const float* Wqkv  = (const float*)d_in[1];
    const float* Wproj = (const float*)d_in[2];
    const float* bproj = (const float*)d_in[3];
    for (int i = 0; i < n_in; ++i) {
        const int s = in_sizes[i];
        if      (s == MTOK * CDIM)       x     = (const float*)d_in[i];
        else if (s == CDIM * 3 * CDIM)   Wqkv  = (const float*)d_in[i];
        else if (s == CDIM * CDIM)       Wproj = (const float*)d_in[i];
        else if (s == CDIM)              bproj = (const float*)d_in[i];
    }
    float* out = (float*)d_out;
    bf16* ws  = (bf16*)d_ws;

    bf16* q  = ws;
    bf16* k  = ws + PERPART;
    bf16* v  = ws + 2 * PERPART;
    bf16* ao = ws + 3 * PERPART;    // attention output [8192, 768] bf16

    // 1) QKV: x[8192,768] @ Wqkv[768,2304] -> q/k/v [b,h,n,d] bf16
    gemm_kernel<3 * CDIM, 0><<<dim3(MTOK / 64, (3 * CDIM) / 64), 256, 0, stream>>>(
        (const void*)x, Wqkv, nullptr, ws, nullptr);
    // 2) flash attention -> ao [b,n,h*d]
    attn_kernel<<<dim3(SEQ / 64, BATCH * NHEADS), 256, 0, stream>>>(q, k, v, ao);
    // 3) proj: ao @ Wproj + bproj -> out (fp32)
    gemm_kernel<CDIM, 1><<<dim3(MTOK / 64, CDIM / 64), 256, 0, stream>>>(
        (const void*)ao, Wproj, bproj, nullptr, out);
}

// Round 6
// 246.619 us; speedup vs baseline: 1.5212x; 1.5212x over previous
//
#include <hip/hip_runtime.h>
#include <math.h>

typedef __bf16 bf16;
typedef __attribute__((ext_vector_type(8))) __bf16 bf16x8;
typedef __attribute__((ext_vector_type(4))) float f32x4;

#define NHEADS 12
#define HDIM 64
#define BATCH 4
#define SEQ 2048
#define CDIM 768
#define MTOK (BATCH * SEQ)                    // 8192 tokens
#define PERPART ((size_t)MTOK * CDIM)         // 6291456 elems

// async 16B global->LDS DMA (gfx950). ldsptr must be wave-uniform; HW adds lane*16.
__device__ static inline void load_lds_16(const void* g, void* l)
{
    __builtin_amdgcn_global_load_lds(
        (const __attribute__((address_space(1))) unsigned int*)g,
        (__attribute__((address_space(3))) unsigned int*)l, 16, 0, 0);
}

// ---------------------------------------------------------------------------
// convert fp32 -> bf16, 8 elems/thread
// ---------------------------------------------------------------------------
__global__ __launch_bounds__(256)
void convert_bf16(const float* __restrict__ in, bf16* __restrict__ out)
{
    const size_t i = ((size_t)blockIdx.x * 256 + threadIdx.x) * 8;
    const float4 v0 = *(const float4*)(in + i);
    const float4 v1 = *(const float4*)(in + i + 4);
    alignas(16) bf16 o[8];
    o[0] = (bf16)v0.x; o[1] = (bf16)v0.y; o[2] = (bf16)v0.z; o[3] = (bf16)v0.w;
    o[4] = (bf16)v1.x; o[5] = (bf16)v1.y; o[6] = (bf16)v1.z; o[7] = (bf16)v1.w;
    *(uint4*)(out + i) = *(const uint4*)o;
}

// ---------------------------------------------------------------------------
// transpose+convert: in fp32 [R][C] -> out bf16 [C][R]; 64x64 tiles
// ---------------------------------------------------------------------------
__global__ __launch_bounds__(256)
void transpose_convert(const float* __restrict__ in, bf16* __restrict__ out,
                       int R, int C)
{
    __shared__ bf16 T[64][65];
    const int r0 = blockIdx.y * 64, c0 = blockIdx.x * 64;
    const int t = threadIdx.x;
    const int ir = t >> 2, ic = (t & 3) * 16;
    #pragma unroll
    for (int e = 0; e < 16; ++e)
        T[ir][ic + e] = (bf16)in[(size_t)(r0 + ir) * C + c0 + ic + e];
    __syncthreads();
    const int oc = t >> 2, orr = (t & 3) * 16;
    alignas(16) bf16 tmp[16];
    #pragma unroll
    for (int e = 0; e < 16; ++e)
        tmp[e] = T[orr + e][oc];
    bf16* dst = out + (size_t)(c0 + oc) * R + r0 + orr;
    *(uint4*)dst       = *(const uint4*)tmp;
    *(uint4*)(dst + 8) = *(const uint4*)(tmp + 8);
}

// ---------------------------------------------------------------------------
// m97-style GEMM: C[M x NCOLS] = A[M x 768] @ Bt^T, A and Bt bf16, Bt = [NCOLS][768].
// 128x128 tile, BK=32, 256 thr = 4 waves (2x2), global_load_lds staging with
// XOR granule swizzle (granule quad ^ row&3) on unpadded [row][32] LDS tiles.
// MODE 0: QKV epilogue -> q,k (scaled 1/8),vT scatter bf16
// MODE 1: proj epilogue -> + bias, fp32 out
// ---------------------------------------------------------------------------
template<int NCOLS, int MODE>
__global__ __launch_bounds__(256)
void gemm128(const bf16* __restrict__ A, const bf16* __restrict__ Bt,
             const float* __restrict__ bias,
             bf16* __restrict__ qb, bf16* __restrict__ kb, bf16* __restrict__ vtb,
             float* __restrict__ outf)
{
    __shared__ bf16 As[128 * 32];
    __shared__ bf16 Bs[128 * 32];

    const int t    = threadIdx.x;
    const int w    = t >> 6, lane = t & 63;
    const int ln   = lane & 15, quad = lane >> 4;
    const int wr   = w >> 1, wc = w & 1;
    const int m0   = blockIdx.x * 128, n0 = blockIdx.y * 128;

    f32x4 acc[4][4] = {};

    for (int k0 = 0; k0 < CDIM; k0 += 32) {
        #pragma unroll
        for (int i = 0; i < 2; ++i) {
            const int S   = (w * 2 + i) * 64 + lane;     // 16B slot id
            const int row = S >> 2, st = S & 3;
            const int g   = st ^ (row & 3);              // global granule to fetch
            load_lds_16(A  + (size_t)(m0 + row) * CDIM + k0 + g * 8,
                        &As[(w * 2 + i) * 512]);
            load_lds_16(Bt + (size_t)(n0 + row) * CDIM + k0 + g * 8,
                        &Bs[(w * 2 + i) * 512]);
        }
        __syncthreads();

        bf16x8 af[4], bf_[4];
        #pragma unroll
        for (int mt = 0; mt < 4; ++mt) {
            const int row = wr * 64 + mt * 16 + ln;
            af[mt] = *(const bf16x8*)&As[row * 32 + (quad ^ (row & 3)) * 8];
        }
        #pragma unroll
        for (int nt = 0; nt < 4; ++nt) {
            const int row = wc * 64 + nt * 16 + ln;
            bf_[nt] = *(const bf16x8*)&Bs[row * 32 + (quad ^ (row & 3)) * 8];
        }
        #pragma unroll
        for (int mt = 0; mt < 4; ++mt)
            #pragma unroll
            for (int nt = 0; nt < 4; ++nt)
                acc[mt][nt] = __builtin_amdgcn_mfma_f32_16x16x32_bf16(
                    af[mt], bf_[nt], acc[mt][nt], 0, 0, 0);
        __syncthreads();
    }

    #pragma unroll
    for (int nt = 0; nt < 4; ++nt) {
        const int c = n0 + wc * 64 + nt * 16 + ln;
        if constexpr (MODE == 0) {
            const int p = c / CDIM, rem = c - p * CDIM;
            const int h = rem >> 6, d = rem & 63;
            #pragma unroll
            for (int mt = 0; mt < 4; ++mt) {
                const int row0 = m0 + wr * 64 + mt * 16 + quad * 4;
                const int b = row0 >> 11, nn = row0 & 2047;
                if (p == 0) {
                    bf16* dst = qb + ((size_t)(b * NHEADS + h) * SEQ + nn) * HDIM + d;
                    #pragma unroll
                    for (int r = 0; r < 4; ++r) dst[r * HDIM] = (bf16)acc[mt][nt][r];
                } else if (p == 1) {
                    // fold softmax scale 1/8 into K (exact exponent shift)
                    bf16* dst = kb + ((size_t)(b * NHEADS + h) * SEQ + nn) * HDIM + d;
                    #pragma unroll
                    for (int r = 0; r < 4; ++r) dst[r * HDIM] = (bf16)(acc[mt][nt][r] * 0.125f);
                } else {
                    // V stored transposed: vT[bh][d][n] -> packed 8B store
                    alignas(8) bf16 pk[4];
                    #pragma unroll
                    for (int r = 0; r < 4; ++r) pk[r] = (bf16)acc[mt][nt][r];
                    *(uint2*)(vtb + ((size_t)(b * NHEADS + h) * HDIM + d) * SEQ + nn) =
                        *(const uint2*)pk;
                }
            }
        } else {
            const float bv = bias[c];
            #pragma unroll
            for (int mt = 0; mt < 4; ++mt) {
                const int row0 = m0 + wr * 64 + mt * 16 + quad * 4;
                #pragma unroll
                for (int r = 0; r < 4; ++r)
                    outf[(size_t)(row0 + r) * CDIM + c] = acc[mt][nt][r] + bv;
            }
        }
    }
}

// ---------------------------------------------------------------------------
// Flash attention, fixed-shift softmax (p = exp(s - 8), shift via MFMA C-init;
// K pre-scaled by 1/8). grid (32, 48), 256 thr = 4 waves, wave w = 16 queries.
// Q/K/Vt staged via global_load_lds into unpadded 64x64 tiles with XOR swizzle
// (granule ^ row&7). V arrives pre-transposed from the QKV epilogue.
// ---------------------------------------------------------------------------
__global__ __launch_bounds__(256)
void attn_kernel(const bf16* __restrict__ Qg, const bf16* __restrict__ Kg,
                 const bf16* __restrict__ Vtg, bf16* __restrict__ Og)
{
    __shared__ bf16 Qs[64 * 64];
    __shared__ bf16 Ks[64 * 64];
    __shared__ bf16 Vs[64 * 64];           // Vs[d][key]
    __shared__ bf16 Ps[4][16 * 72];        // per-wave P, padded stride 72

    const int t    = threadIdx.x;
    const int w    = t >> 6, lane = t & 63;
    const int ln   = lane & 15, quad = lane >> 4;
    const int bh   = blockIdx.y, q0 = blockIdx.x * 64;

    const bf16* Qb = Qg  + (size_t)bh * SEQ * HDIM;
    const bf16* Kb = Kg  + (size_t)bh * SEQ * HDIM;
    const bf16* Vb = Vtg + (size_t)bh * HDIM * SEQ;

    // stage Q once (published by iter-0's barrier)
    #pragma unroll
    for (int i = 0; i < 2; ++i) {
        const int S = (w * 2 + i) * 64 + lane;
        const int row = S >> 3, g = (S & 7) ^ (row & 7);
        load_lds_16(Qb + (size_t)(q0 + row) * HDIM + g * 8, &Qs[(w * 2 + i) * 512]);
    }

    f32x4 o_acc[4] = {};
    float rs[4] = {0.f, 0.f, 0.f, 0.f};

    for (int kb = 0; kb < SEQ / 64; ++kb) {
        #pragma unroll
        for (int i = 0; i < 2; ++i) {
            const int S = (w * 2 + i) * 64 + lane;
            const int row = S >> 3, g = (S & 7) ^ (row & 7);
            load_lds_16(Kb + (size_t)(kb * 64 + row) * HDIM + g * 8,
                        &Ks[(w * 2 + i) * 512]);
            load_lds_16(Vb + (size_t)row * SEQ + kb * 64 + g * 8,
                        &Vs[(w * 2 + i) * 512]);
        }
        __syncthreads();

        // S = q k^T/8 - 8  (shift via C-init, scale pre-folded in K)
        bf16x8 qa[2];
        #pragma unroll
        for (int kk = 0; kk < 2; ++kk) {
            const int row = w * 16 + ln;
            const int st = (kk * 4 + quad) ^ (row & 7);
            qa[kk] = *(const bf16x8*)&Qs[row * 64 + st * 8];
        }
        f32x4 s[4];
        #pragma unroll
        for (int nt = 0; nt < 4; ++nt) {
            f32x4 a = {-8.f, -8.f, -8.f, -8.f};
            #pragma unroll
            for (int kk = 0; kk < 2; ++kk) {
                const int row = nt * 16 + ln;
                const int st = (kk * 4 + quad) ^ (row & 7);
                const bf16x8 kf = *(const bf16x8*)&Ks[row * 64 + st * 8];
                a = __builtin_amdgcn_mfma_f32_16x16x32_bf16(qa[kk], kf, a, 0, 0, 0);
            }
            s[nt] = a;
        }

        // p = exp(s); accumulate row sums; C/D -> A layout via per-wave LDS
        #pragma unroll
        for (int nt = 0; nt < 4; ++nt)
            #pragma unroll
            for (int r = 0; r < 4; ++r) {
                const float p = __expf(s[nt][r]);
                rs[r] += p;
                Ps[w][(quad * 4 + r) * 72 + nt * 16 + ln] = (bf16)p;
            }

        // O += P V (Ps wave-local: no barrier, compiler inserts lgkmcnt)
        #pragma unroll
        for (int kk = 0; kk < 2; ++kk) {
            const bf16x8 pa = *(const bf16x8*)&Ps[w][ln * 72 + kk * 32 + quad * 8];
            #pragma unroll
            for (int nt = 0; nt < 4; ++nt) {
                const int row = nt * 16 + ln;
                const int st = (kk * 4 + quad) ^ (row & 7);
                const bf16x8 vf = *(const bf16x8*)&Vs[row * 64 + st * 8];
                o_acc[nt] = __builtin_amdgcn_mfma_f32_16x16x32_bf16(pa, vf, o_acc[nt], 0, 0, 0);
            }
        }
        __syncthreads();   // protect Ks/Vs before next stage
    }

    // final l reduction across the 16 lanes holding each row
    #pragma unroll
    for (int off = 1; off < 16; off <<= 1)
        #pragma unroll
        for (int r = 0; r < 4; ++r)
            rs[r] += __shfl_xor(rs[r], off);

    const int b = bh / NHEADS, h = bh % NHEADS;
    #pragma unroll
    for (int nt = 0; nt < 4; ++nt) {
        const int d = nt * 16 + ln;
        #pragma unroll
        for (int r = 0; r < 4; ++r) {
            const int q = q0 + w * 16 + quad * 4 + r;
            Og[(size_t)(b * SEQ + q) * CDIM + h * HDIM + d] = (bf16)(o_acc[nt][r] / rs[r]);
        }
    }
}

// ---------------------------------------------------------------------------
extern "C" void kernel_launch(void* const* d_in, const int* in_sizes, int n_in,
                              void* d_out, int out_size, void* d_ws, size_t ws_size,
                              hipStream_t stream)
{
    const float* x     = (const float*)d_in[0];
    const float* Wqkv  = (const float*)d_in[1];
    const float* Wproj = (const float*)d_in[2];
    const float* bproj = (const float*)d_in[3];
    float* out = (float*)d_out;

    bf16* ws   = (bf16*)d_ws;
    bf16* xb   = ws;                                   // [8192][768]
    bf16* wqt  = xb  + PERPART;                        // [2304][768]
    bf16* wpt  = wqt + (size_t)3 * CDIM * CDIM;        // [768][768]
    bf16* q    = wpt + (size_t)CDIM * CDIM;            // [bh][2048][64]
    bf16* k    = q   + PERPART;
    bf16* vt   = k   + PERPART;                        // [bh][64][2048]
    bf16* ao   = vt  + PERPART;                        // [8192][768]

    // precompute: convert x, transpose-convert weights
    convert_bf16<<<dim3(PERPART / (256 * 8)), 256, 0, stream>>>(x, xb);
    transpose_convert<<<dim3(3 * CDIM / 64, CDIM / 64), 256, 0, stream>>>(
        Wqkv, wqt, CDIM, 3 * CDIM);
    transpose_convert<<<dim3(CDIM / 64, CDIM / 64), 256, 0, stream>>>(
        Wproj, wpt, CDIM, CDIM);

    // 1) QKV GEMM -> q, k(/8), vT
    gemm128<3 * CDIM, 0><<<dim3(MTOK / 128, 3 * CDIM / 128), 256, 0, stream>>>(
        xb, wqt, nullptr, q, k, vt, nullptr);
    // 2) attention -> ao bf16
    attn_kernel<<<dim3(SEQ / 64, BATCH * NHEADS), 256, 0, stream>>>(q, k, vt, ao);
    // 3) proj -> out fp32
    gemm128<CDIM, 1><<<dim3(MTOK / 128, CDIM / 128), 256, 0, stream>>>(
        ao, wpt, bproj, nullptr, nullptr, nullptr, out);
}

// Round 8
// 246.554 us; speedup vs baseline: 1.5216x; 1.0003x over previous
//
#include <hip/hip_runtime.h>
#include <math.h>

typedef __bf16 bf16;
typedef __attribute__((ext_vector_type(8))) __bf16 bf16x8;
typedef __attribute__((ext_vector_type(4))) __bf16 bf16x4;
typedef __attribute__((ext_vector_type(4))) short i16x4;
typedef __attribute__((ext_vector_type(4))) float f32x4;

#define NHEADS 12
#define HDIM 64
#define BATCH 4
#define SEQ 2048
#define CDIM 768
#define MTOK (BATCH * SEQ)                    // 8192 tokens
#define PERPART ((size_t)MTOK * CDIM)         // 6291456 elems

// K pre-scale: log2(e)/8 -> softmax exp becomes a single v_exp_f32 (2^x)
#define KSCALE 0.18033688011112042f
// constant shift inside exp2 (cancels exactly in normalization)
#define SHIFT 11.54156032f

// async 16B global->LDS DMA (gfx950). lds ptr wave-uniform; HW adds lane*16.
// NB: one wave-instruction covers 64 granules = 1024 B = 512 bf16 elements.
__device__ static inline void load_lds_16(const void* g, void* l)
{
    __builtin_amdgcn_global_load_lds(
        (const __attribute__((address_space(1))) unsigned int*)g,
        (__attribute__((address_space(3))) unsigned int*)l, 16, 0, 0);
}

__device__ static inline i16x4 as_i16x4(bf16x4 v)
{
    union { bf16x4 b; i16x4 i; } u;
    u.b = v;
    return u.i;
}

// ---------------------------------------------------------------------------
// convert fp32 -> bf16, 8 elems/thread
// ---------------------------------------------------------------------------
__global__ __launch_bounds__(256)
void convert_bf16(const float* __restrict__ in, bf16* __restrict__ out)
{
    const size_t i = ((size_t)blockIdx.x * 256 + threadIdx.x) * 8;
    const float4 v0 = *(const float4*)(in + i);
    const float4 v1 = *(const float4*)(in + i + 4);
    alignas(16) bf16 o[8];
    o[0] = (bf16)v0.x; o[1] = (bf16)v0.y; o[2] = (bf16)v0.z; o[3] = (bf16)v0.w;
    o[4] = (bf16)v1.x; o[5] = (bf16)v1.y; o[6] = (bf16)v1.z; o[7] = (bf16)v1.w;
    *(uint4*)(out + i) = *(const uint4*)o;
}

// ---------------------------------------------------------------------------
// transpose+convert: in fp32 [R][C] -> out bf16 [C][R]; 64x64 tiles
// ---------------------------------------------------------------------------
__global__ __launch_bounds__(256)
void transpose_convert(const float* __restrict__ in, bf16* __restrict__ out,
                       int R, int C)
{
    __shared__ bf16 T[64][65];
    const int r0 = blockIdx.y * 64, c0 = blockIdx.x * 64;
    const int t = threadIdx.x;
    const int ir = t >> 2, ic = (t & 3) * 16;
    #pragma unroll
    for (int e = 0; e < 16; ++e)
        T[ir][ic + e] = (bf16)in[(size_t)(r0 + ir) * C + c0 + ic + e];
    __syncthreads();
    const int oc = t >> 2, orr = (t & 3) * 16;
    alignas(16) bf16 tmp[16];
    #pragma unroll
    for (int e = 0; e < 16; ++e)
        tmp[e] = T[orr + e][oc];
    bf16* dst = out + (size_t)(c0 + oc) * R + r0 + orr;
    *(uint4*)dst       = *(const uint4*)tmp;
    *(uint4*)(dst + 8) = *(const uint4*)(tmp + 8);
}

// ---------------------------------------------------------------------------
// m97-style GEMM: C[M x NCOLS] = A[M x 768] @ Bt^T. 128x128 tile, BK=32,
// 4 waves (2x2). MODE 0: QKV epilogue -> q, k(*log2e/8), vT scatter bf16.
// MODE 1: proj epilogue -> + bias, fp32 out.
// ---------------------------------------------------------------------------
template<int NCOLS, int MODE>
__global__ __launch_bounds__(256)
void gemm128(const bf16* __restrict__ A, const bf16* __restrict__ Bt,
             const float* __restrict__ bias,
             bf16* __restrict__ qb, bf16* __restrict__ kb, bf16* __restrict__ vtb,
             float* __restrict__ outf)
{
    __shared__ bf16 As[128 * 32];
    __shared__ bf16 Bs[128 * 32];

    const int t    = threadIdx.x;
    const int w    = t >> 6, lane = t & 63;
    const int ln   = lane & 15, quad = lane >> 4;
    const int wr   = w >> 1, wc = w & 1;
    const int m0   = blockIdx.x * 128, n0 = blockIdx.y * 128;

    f32x4 acc[4][4] = {};

    for (int k0 = 0; k0 < CDIM; k0 += 32) {
        #pragma unroll
        for (int i = 0; i < 2; ++i) {
            const int S   = (w * 2 + i) * 64 + lane;     // 16B slot id
            const int row = S >> 2, st = S & 3;
            const int g   = st ^ (row & 3);
            load_lds_16(A  + (size_t)(m0 + row) * CDIM + k0 + g * 8,
                        &As[(w * 2 + i) * 512]);
            load_lds_16(Bt + (size_t)(n0 + row) * CDIM + k0 + g * 8,
                        &Bs[(w * 2 + i) * 512]);
        }
        __syncthreads();

        bf16x8 af[4], bf_[4];
        #pragma unroll
        for (int mt = 0; mt < 4; ++mt) {
            const int row = wr * 64 + mt * 16 + ln;
            af[mt] = *(const bf16x8*)&As[row * 32 + (quad ^ (row & 3)) * 8];
        }
        #pragma unroll
        for (int nt = 0; nt < 4; ++nt) {
            const int row = wc * 64 + nt * 16 + ln;
            bf_[nt] = *(const bf16x8*)&Bs[row * 32 + (quad ^ (row & 3)) * 8];
        }
        #pragma unroll
        for (int mt = 0; mt < 4; ++mt)
            #pragma unroll
            for (int nt = 0; nt < 4; ++nt)
                acc[mt][nt] = __builtin_amdgcn_mfma_f32_16x16x32_bf16(
                    af[mt], bf_[nt], acc[mt][nt], 0, 0, 0);
        __syncthreads();
    }

    #pragma unroll
    for (int nt = 0; nt < 4; ++nt) {
        const int c = n0 + wc * 64 + nt * 16 + ln;
        if constexpr (MODE == 0) {
            const int p = c / CDIM, rem = c - p * CDIM;
            const int h = rem >> 6, d = rem & 63;
            #pragma unroll
            for (int mt = 0; mt < 4; ++mt) {
                const int row0 = m0 + wr * 64 + mt * 16 + quad * 4;
                const int b = row0 >> 11, nn = row0 & 2047;
                if (p == 0) {
                    bf16* dst = qb + ((size_t)(b * NHEADS + h) * SEQ + nn) * HDIM + d;
                    #pragma unroll
                    for (int r = 0; r < 4; ++r) dst[r * HDIM] = (bf16)acc[mt][nt][r];
                } else if (p == 1) {
                    bf16* dst = kb + ((size_t)(b * NHEADS + h) * SEQ + nn) * HDIM + d;
                    #pragma unroll
                    for (int r = 0; r < 4; ++r) dst[r * HDIM] = (bf16)(acc[mt][nt][r] * KSCALE);
                } else {
                    alignas(8) bf16 pk[4];
                    #pragma unroll
                    for (int r = 0; r < 4; ++r) pk[r] = (bf16)acc[mt][nt][r];
                    *(uint2*)(vtb + ((size_t)(b * NHEADS + h) * HDIM + d) * SEQ + nn) =
                        *(const uint2*)pk;
                }
            }
        } else {
            const float bv = bias[c];
            #pragma unroll
            for (int mt = 0; mt < 4; ++mt) {
                const int row0 = m0 + wr * 64 + mt * 16 + quad * 4;
                #pragma unroll
                for (int r = 0; r < 4; ++r)
                    outf[(size_t)(row0 + r) * CDIM + c] = acc[mt][nt][r] + bv;
            }
        }
    }
}

// ---------------------------------------------------------------------------
// Flash attention v3 (fixed staging offsets): grid (SEQ/128, B*H), 4 waves,
// wave = 32 q. S^T = K*(Q^T) via 16x16x32 -> exp2 in regs -> PV via 16x16x16
// whose A-operand layout coincides with S^T's C/D layout (zero P traffic).
// K pre-scaled by log2e/8; shift -SHIFT folded into MFMA C-init.
// ---------------------------------------------------------------------------
__global__ __launch_bounds__(256)
void attn_kernel(const bf16* __restrict__ Qg, const bf16* __restrict__ Kg,
                 const bf16* __restrict__ Vtg, bf16* __restrict__ Og)
{
    __shared__ bf16 Qs[128 * 64];          // [q_local][d], XOR-swizzled granules
    __shared__ bf16 Ks[64 * 64];           // [key][d]
    __shared__ bf16 Vs[64 * 64];           // [d][key]

    const int t    = threadIdx.x;
    const int w    = t >> 6, lane = t & 63;
    const int ln   = lane & 15, quad = lane >> 4;
    const int bh   = blockIdx.y, q0 = blockIdx.x * 128;

    const bf16* Qb = Qg  + (size_t)bh * SEQ * HDIM;
    const bf16* Kb = Kg  + (size_t)bh * SEQ * HDIM;
    const bf16* Vb = Vtg + (size_t)bh * HDIM * SEQ;

    // stage Q once: 1024 granules, 16 wave-instr; 64 granules = 512 ELEMS each
    #pragma unroll
    for (int i = 0; i < 4; ++i) {
        const int S = (w * 4 + i) * 64 + lane;
        const int row = S >> 3, g = (S & 7) ^ (row & 7);
        load_lds_16(Qb + (size_t)(q0 + row) * HDIM + g * 8, &Qs[(w * 4 + i) * 512]);
    }
    __syncthreads();

    // hoist Q B-frags (stable across all key blocks): qf[qt][kk]
    bf16x8 qf[2][2];
    #pragma unroll
    for (int qt = 0; qt < 2; ++qt)
        #pragma unroll
        for (int kk = 0; kk < 2; ++kk) {
            const int row = w * 32 + qt * 16 + ln;
            const int g = (kk * 4 + quad) ^ (row & 7);
            qf[qt][kk] = *(const bf16x8*)&Qs[row * 64 + g * 8];
        }

    f32x4 o_acc[2][4] = {};
    float rs[2] = {0.f, 0.f};

    for (int kb = 0; kb < SEQ / 64; ++kb) {
        // stage K (8KB) + Vt (8KB): 64-granule groups = 512-elem stride
        #pragma unroll
        for (int i = 0; i < 2; ++i) {
            const int S = (w * 2 + i) * 64 + lane;
            const int row = S >> 3, g = (S & 7) ^ (row & 7);
            load_lds_16(Kb + (size_t)(kb * 64 + row) * HDIM + g * 8,
                        &Ks[(w * 2 + i) * 512]);
            load_lds_16(Vb + (size_t)row * SEQ + kb * 64 + g * 8,
                        &Vs[(w * 2 + i) * 512]);
        }
        __syncthreads();

        #pragma unroll
        for (int mt = 0; mt < 4; ++mt) {       // key 16-tiles
            // K A-frags for this key tile
            bf16x8 ka[2];
            #pragma unroll
            for (int kk = 0; kk < 2; ++kk) {
                const int row = mt * 16 + ln;
                const int g = (kk * 4 + quad) ^ (row & 7);
                ka[kk] = *(const bf16x8*)&Ks[row * 64 + g * 8];
            }
            // S^T[key][q] tiles, shift folded into C-init
            f32x4 s[2];
            #pragma unroll
            for (int qt = 0; qt < 2; ++qt) {
                f32x4 a = {-SHIFT, -SHIFT, -SHIFT, -SHIFT};
                a = __builtin_amdgcn_mfma_f32_16x16x32_bf16(ka[0], qf[qt][0], a, 0, 0, 0);
                a = __builtin_amdgcn_mfma_f32_16x16x32_bf16(ka[1], qf[qt][1], a, 0, 0, 0);
                s[qt] = a;
            }
            // p = 2^s; row-sum partials; pack to 16x16x16 A-frags (j == r!)
            i16x4 pf[2];
            #pragma unroll
            for (int qt = 0; qt < 2; ++qt) {
                float p0 = exp2f(s[qt][0]), p1 = exp2f(s[qt][1]);
                float p2 = exp2f(s[qt][2]), p3 = exp2f(s[qt][3]);
                rs[qt] += (p0 + p1) + (p2 + p3);
                bf16x4 pb = { (bf16)p0, (bf16)p1, (bf16)p2, (bf16)p3 };
                pf[qt] = as_i16x4(pb);
            }
            // O[q][d] += P(16 keys) * V : V B-frags b64 from Vs[d][key]
            #pragma unroll
            for (int dt = 0; dt < 4; ++dt) {
                const int row = dt * 16 + ln;                 // d
                const int G = mt * 2 + (quad >> 1);           // key 16B-granule
                const int g = G ^ (row & 7);
                const bf16x4 vf = *(const bf16x4*)&Vs[row * 64 + g * 8 + (quad & 1) * 4];
                const i16x4 vi = as_i16x4(vf);
                #pragma unroll
                for (int qt = 0; qt < 2; ++qt)
                    o_acc[qt][dt] = __builtin_amdgcn_mfma_f32_16x16x16bf16_1k(
                        pf[qt], vi, o_acc[qt][dt], 0, 0, 0);
            }
        }
        __syncthreads();   // protect Ks/Vs before next staging
    }

    // rs: lane (ln,quad) holds partial for q=qt*16+ln; reduce across quads
    #pragma unroll
    for (int qt = 0; qt < 2; ++qt) {
        rs[qt] += __shfl_xor(rs[qt], 16);
        rs[qt] += __shfl_xor(rs[qt], 32);
    }
    // O rows are q = qt*16 + quad*4 + r -> fetch inverse sums via shfl
    float inv[2][4];
    #pragma unroll
    for (int qt = 0; qt < 2; ++qt)
        #pragma unroll
        for (int r = 0; r < 4; ++r)
            inv[qt][r] = 1.0f / __shfl(rs[qt], quad * 4 + r);

    const int b = bh / NHEADS, h = bh % NHEADS;
    #pragma unroll
    for (int qt = 0; qt < 2; ++qt)
        #pragma unroll
        for (int dt = 0; dt < 4; ++dt) {
            const int d = dt * 16 + ln;
            #pragma unroll
            for (int r = 0; r < 4; ++r) {
                const int q = q0 + w * 32 + qt * 16 + quad * 4 + r;
                Og[(size_t)(b * SEQ + q) * CDIM + h * HDIM + d] =
                    (bf16)(o_acc[qt][dt][r] * inv[qt][r]);
            }
        }
}

// ---------------------------------------------------------------------------
extern "C" void kernel_launch(void* const* d_in, const int* in_sizes, int n_in,
                              void* d_out, int out_size, void* d_ws, size_t ws_size,
                              hipStream_t stream)
{
    const float* x     = (const float*)d_in[0];
    const float* Wqkv  = (const float*)d_in[1];
    const float* Wproj = (const float*)d_in[2];
    const float* bproj = (const float*)d_in[3];
    float* out = (float*)d_out;

    bf16* ws   = (bf16*)d_ws;
    bf16* xb   = ws;                                   // [8192][768]
    bf16* wqt  = xb  + PERPART;                        // [2304][768]
    bf16* wpt  = wqt + (size_t)3 * CDIM * CDIM;        // [768][768]
    bf16* q    = wpt + (size_t)CDIM * CDIM;            // [bh][2048][64]
    bf16* k    = q   + PERPART;                        // scaled by log2e/8
    bf16* vt   = k   + PERPART;                        // [bh][64][2048]
    bf16* ao   = vt  + PERPART;                        // [8192][768]

    convert_bf16<<<dim3(PERPART / (256 * 8)), 256, 0, stream>>>(x, xb);
    transpose_convert<<<dim3(3 * CDIM / 64, CDIM / 64), 256, 0, stream>>>(
        Wqkv, wqt, CDIM, 3 * CDIM);
    transpose_convert<<<dim3(CDIM / 64, CDIM / 64), 256, 0, stream>>>(
        Wproj, wpt, CDIM, CDIM);

    gemm128<3 * CDIM, 0><<<dim3(MTOK / 128, 3 * CDIM / 128), 256, 0, stream>>>(
        xb, wqt, nullptr, q, k, vt, nullptr);
    attn_kernel<<<dim3(SEQ / 128, BATCH * NHEADS), 256, 0, stream>>>(q, k, vt, ao);
    gemm128<CDIM, 1><<<dim3(MTOK / 128, CDIM / 128), 256, 0, stream>>>(
        ao, wpt, bproj, nullptr, nullptr, nullptr, out);
}

// Round 9
// 243.083 us; speedup vs baseline: 1.5434x; 1.0143x over previous
//
#include <hip/hip_runtime.h>
#include <math.h>

typedef __bf16 bf16;
typedef __attribute__((ext_vector_type(8))) __bf16 bf16x8;
typedef __attribute__((ext_vector_type(4))) __bf16 bf16x4;
typedef __attribute__((ext_vector_type(4))) float f32x4;

#define NHEADS 12
#define HDIM 64
#define BATCH 4
#define SEQ 2048
#define CDIM 768
#define MTOK (BATCH * SEQ)                    // 8192 tokens
#define PERPART ((size_t)MTOK * CDIM)         // 6291456 elems
#define NKB (SEQ / 64)                        // 32 key blocks

// K pre-scale: log2(e)/8 -> softmax exp becomes a single 2^x
#define KSCALE 0.18033688011112042f
// constant shift inside exp2 (cancels exactly in normalization)
#define SHIFT 11.54156032f

// async 16B global->LDS DMA (gfx950). lds ptr wave-uniform; HW adds lane*16.
// NB: one wave-instruction covers 64 granules = 1024 B = 512 bf16 elements.
__device__ static inline void load_lds_16(const void* g, void* l)
{
    __builtin_amdgcn_global_load_lds(
        (const __attribute__((address_space(1))) unsigned int*)g,
        (__attribute__((address_space(3))) unsigned int*)l, 16, 0, 0);
}

// ---------------------------------------------------------------------------
// convert fp32 -> bf16, 8 elems/thread
// ---------------------------------------------------------------------------
__global__ __launch_bounds__(256)
void convert_bf16(const float* __restrict__ in, bf16* __restrict__ out)
{
    const size_t i = ((size_t)blockIdx.x * 256 + threadIdx.x) * 8;
    const float4 v0 = *(const float4*)(in + i);
    const float4 v1 = *(const float4*)(in + i + 4);
    alignas(16) bf16 o[8];
    o[0] = (bf16)v0.x; o[1] = (bf16)v0.y; o[2] = (bf16)v0.z; o[3] = (bf16)v0.w;
    o[4] = (bf16)v1.x; o[5] = (bf16)v1.y; o[6] = (bf16)v1.z; o[7] = (bf16)v1.w;
    *(uint4*)(out + i) = *(const uint4*)o;
}

// ---------------------------------------------------------------------------
// transpose+convert: in fp32 [R][C] -> out bf16 [C][R]; 64x64 tiles
// ---------------------------------------------------------------------------
__global__ __launch_bounds__(256)
void transpose_convert(const float* __restrict__ in, bf16* __restrict__ out,
                       int R, int C)
{
    __shared__ bf16 T[64][65];
    const int r0 = blockIdx.y * 64, c0 = blockIdx.x * 64;
    const int t = threadIdx.x;
    const int ir = t >> 2, ic = (t & 3) * 16;
    #pragma unroll
    for (int e = 0; e < 16; ++e)
        T[ir][ic + e] = (bf16)in[(size_t)(r0 + ir) * C + c0 + ic + e];
    __syncthreads();
    const int oc = t >> 2, orr = (t & 3) * 16;
    alignas(16) bf16 tmp[16];
    #pragma unroll
    for (int e = 0; e < 16; ++e)
        tmp[e] = T[orr + e][oc];
    bf16* dst = out + (size_t)(c0 + oc) * R + r0 + orr;
    *(uint4*)dst       = *(const uint4*)tmp;
    *(uint4*)(dst + 8) = *(const uint4*)(tmp + 8);
}

// ---------------------------------------------------------------------------
// m97-style GEMM (unchanged): C[M x NCOLS] = A[M x 768] @ Bt^T. 128x128 tile,
// BK=32, 4 waves (2x2). MODE 0: QKV epilogue -> q, k(*log2e/8), vT bf16.
// MODE 1: proj epilogue -> + bias, fp32 out.
// ---------------------------------------------------------------------------
template<int NCOLS, int MODE>
__global__ __launch_bounds__(256)
void gemm128(const bf16* __restrict__ A, const bf16* __restrict__ Bt,
             const float* __restrict__ bias,
             bf16* __restrict__ qb, bf16* __restrict__ kb, bf16* __restrict__ vtb,
             float* __restrict__ outf)
{
    __shared__ bf16 As[128 * 32];
    __shared__ bf16 Bs[128 * 32];

    const int t    = threadIdx.x;
    const int w    = t >> 6, lane = t & 63;
    const int ln   = lane & 15, quad = lane >> 4;
    const int wr   = w >> 1, wc = w & 1;
    const int m0   = blockIdx.x * 128, n0 = blockIdx.y * 128;

    f32x4 acc[4][4] = {};

    for (int k0 = 0; k0 < CDIM; k0 += 32) {
        #pragma unroll
        for (int i = 0; i < 2; ++i) {
            const int S   = (w * 2 + i) * 64 + lane;     // 16B slot id
            const int row = S >> 2, st = S & 3;
            const int g   = st ^ (row & 3);
            load_lds_16(A  + (size_t)(m0 + row) * CDIM + k0 + g * 8,
                        &As[(w * 2 + i) * 512]);
            load_lds_16(Bt + (size_t)(n0 + row) * CDIM + k0 + g * 8,
                        &Bs[(w * 2 + i) * 512]);
        }
        __syncthreads();

        bf16x8 af[4], bf_[4];
        #pragma unroll
        for (int mt = 0; mt < 4; ++mt) {
            const int row = wr * 64 + mt * 16 + ln;
            af[mt] = *(const bf16x8*)&As[row * 32 + (quad ^ (row & 3)) * 8];
        }
        #pragma unroll
        for (int nt = 0; nt < 4; ++nt) {
            const int row = wc * 64 + nt * 16 + ln;
            bf_[nt] = *(const bf16x8*)&Bs[row * 32 + (quad ^ (row & 3)) * 8];
        }
        #pragma unroll
        for (int mt = 0; mt < 4; ++mt)
            #pragma unroll
            for (int nt = 0; nt < 4; ++nt)
                acc[mt][nt] = __builtin_amdgcn_mfma_f32_16x16x32_bf16(
                    af[mt], bf_[nt], acc[mt][nt], 0, 0, 0);
        __syncthreads();
    }

    #pragma unroll
    for (int nt = 0; nt < 4; ++nt) {
        const int c = n0 + wc * 64 + nt * 16 + ln;
        if constexpr (MODE == 0) {
            const int p = c / CDIM, rem = c - p * CDIM;
            const int h = rem >> 6, d = rem & 63;
            #pragma unroll
            for (int mt = 0; mt < 4; ++mt) {
                const int row0 = m0 + wr * 64 + mt * 16 + quad * 4;
                const int b = row0 >> 11, nn = row0 & 2047;
                if (p == 0) {
                    bf16* dst = qb + ((size_t)(b * NHEADS + h) * SEQ + nn) * HDIM + d;
                    #pragma unroll
                    for (int r = 0; r < 4; ++r) dst[r * HDIM] = (bf16)acc[mt][nt][r];
                } else if (p == 1) {
                    bf16* dst = kb + ((size_t)(b * NHEADS + h) * SEQ + nn) * HDIM + d;
                    #pragma unroll
                    for (int r = 0; r < 4; ++r) dst[r * HDIM] = (bf16)(acc[mt][nt][r] * KSCALE);
                } else {
                    alignas(8) bf16 pk[4];
                    #pragma unroll
                    for (int r = 0; r < 4; ++r) pk[r] = (bf16)acc[mt][nt][r];
                    *(uint2*)(vtb + ((size_t)(b * NHEADS + h) * HDIM + d) * SEQ + nn) =
                        *(const uint2*)pk;
                }
            }
        } else {
            const float bv = bias[c];
            #pragma unroll
            for (int mt = 0; mt < 4; ++mt) {
                const int row0 = m0 + wr * 64 + mt * 16 + quad * 4;
                #pragma unroll
                for (int r = 0; r < 4; ++r)
                    outf[(size_t)(row0 + r) * CDIM + c] = acc[mt][nt][r] + bv;
            }
        }
    }
}

// ---------------------------------------------------------------------------
// Flash attention v4: double-buffered K/V with prefetch-before-compute
// (drain of the DMA overlaps the compute phase; ONE barrier per kb), and PV
// via 16x16x32 (two 16-key S^T tiles concatenated into one A/B-frag pair).
// grid (SEQ/128, B*H), 4 waves, wave = 32 q. K pre-scaled by log2e/8.
// ---------------------------------------------------------------------------
__global__ __launch_bounds__(256)
void attn_kernel(const bf16* __restrict__ Qg, const bf16* __restrict__ Kg,
                 const bf16* __restrict__ Vtg, bf16* __restrict__ Og)
{
    __shared__ bf16 Qs[128 * 64];          // [q_local][d], XOR-swizzled granules
    __shared__ bf16 Ks[2][64 * 64];        // [key][d], double-buffered
    __shared__ bf16 Vs[2][64 * 64];        // [d][key], double-buffered

    const int t    = threadIdx.x;
    const int w    = t >> 6, lane = t & 63;
    const int ln   = lane & 15, quad = lane >> 4;
    const int bh   = blockIdx.y, q0 = blockIdx.x * 128;

    const bf16* Qb = Qg  + (size_t)bh * SEQ * HDIM;
    const bf16* Kb = Kg  + (size_t)bh * SEQ * HDIM;
    const bf16* Vb = Vtg + (size_t)bh * HDIM * SEQ;

    // staging geometry (shared by Q/K/V stages)
    const int S2 = w * 2 * 64 + lane;      // used per 2-group stages

    // stage Q (16 wave-instr) + K/V block 0 into buf 0
    #pragma unroll
    for (int i = 0; i < 4; ++i) {
        const int S = (w * 4 + i) * 64 + lane;
        const int row = S >> 3, g = (S & 7) ^ (row & 7);
        load_lds_16(Qb + (size_t)(q0 + row) * HDIM + g * 8, &Qs[(w * 4 + i) * 512]);
    }
    #pragma unroll
    for (int i = 0; i < 2; ++i) {
        const int S = S2 + i * 64;
        const int row = S >> 3, g = (S & 7) ^ (row & 7);
        load_lds_16(Kb + (size_t)row * HDIM + g * 8, &Ks[0][(w * 2 + i) * 512]);
        load_lds_16(Vb + (size_t)row * SEQ + g * 8,  &Vs[0][(w * 2 + i) * 512]);
    }
    __syncthreads();

    // hoist Q B-frags (stable across all key blocks)
    bf16x8 qf[2][2];
    #pragma unroll
    for (int qt = 0; qt < 2; ++qt)
        #pragma unroll
        for (int kk = 0; kk < 2; ++kk) {
            const int row = w * 32 + qt * 16 + ln;
            const int g = (kk * 4 + quad) ^ (row & 7);
            qf[qt][kk] = *(const bf16x8*)&Qs[row * 64 + g * 8];
        }

    f32x4 o_acc[2][4] = {};
    float rs[2] = {0.f, 0.f};

    for (int kb = 0; kb < NKB; ++kb) {
        // prefetch next K/V block into the other buffer (drains at the
        // barrier BELOW, i.e. after a full compute phase in flight)
        if (kb + 1 < NKB) {
            const int nb = (kb + 1) & 1;
            #pragma unroll
            for (int i = 0; i < 2; ++i) {
                const int S = S2 + i * 64;
                const int row = S >> 3, g = (S & 7) ^ (row & 7);
                load_lds_16(Kb + (size_t)((kb + 1) * 64 + row) * HDIM + g * 8,
                            &Ks[nb][(w * 2 + i) * 512]);
                load_lds_16(Vb + (size_t)row * SEQ + (kb + 1) * 64 + g * 8,
                            &Vs[nb][(w * 2 + i) * 512]);
            }
        }

        const bf16* Ksb = Ks[kb & 1];
        const bf16* Vsb = Vs[kb & 1];

        #pragma unroll
        for (int p = 0; p < 2; ++p) {          // pair of 16-key tiles
            union { bf16x8 v8; bf16x4 v4[2]; } pf8[2];
            #pragma unroll
            for (int sub = 0; sub < 2; ++sub) {
                const int mt = p * 2 + sub;
                bf16x8 ka[2];
                #pragma unroll
                for (int kk = 0; kk < 2; ++kk) {
                    const int row = mt * 16 + ln;
                    const int g = (kk * 4 + quad) ^ (row & 7);
                    ka[kk] = *(const bf16x8*)&Ksb[row * 64 + g * 8];
                }
                #pragma unroll
                for (int qt = 0; qt < 2; ++qt) {
                    f32x4 a = {-SHIFT, -SHIFT, -SHIFT, -SHIFT};
                    a = __builtin_amdgcn_mfma_f32_16x16x32_bf16(ka[0], qf[qt][0], a, 0, 0, 0);
                    a = __builtin_amdgcn_mfma_f32_16x16x32_bf16(ka[1], qf[qt][1], a, 0, 0, 0);
                    const float p0 = exp2f(a[0]), p1 = exp2f(a[1]);
                    const float p2 = exp2f(a[2]), p3 = exp2f(a[3]);
                    rs[qt] += (p0 + p1) + (p2 + p3);
                    bf16x4 pb = { (bf16)p0, (bf16)p1, (bf16)p2, (bf16)p3 };
                    pf8[qt].v4[sub] = pb;
                }
            }
            // O += P(32 keys) * V via 16x16x32; key enumeration
            // (quad,j) -> t_{j>>2}*16 + quad*4 + (j&3) on both operands
            #pragma unroll
            for (int dt = 0; dt < 4; ++dt) {
                const int row = dt * 16 + ln;               // d
                union { bf16x8 v8; bf16x4 v4[2]; } vv;
                #pragma unroll
                for (int sub = 0; sub < 2; ++sub) {
                    const int G = (p * 2 + sub) * 2 + (quad >> 1);
                    const int g = G ^ (row & 7);
                    vv.v4[sub] = *(const bf16x4*)&Vsb[row * 64 + g * 8 + (quad & 1) * 4];
                }
                #pragma unroll
                for (int qt = 0; qt < 2; ++qt)
                    o_acc[qt][dt] = __builtin_amdgcn_mfma_f32_16x16x32_bf16(
                        pf8[qt].v8, vv.v8, o_acc[qt][dt], 0, 0, 0);
            }
        }
        __syncthreads();   // drains prefetch (overlapped) + guards buffer swap
    }

    // rs: lane (ln,quad) holds partial for q=qt*16+ln; reduce across quads
    #pragma unroll
    for (int qt = 0; qt < 2; ++qt) {
        rs[qt] += __shfl_xor(rs[qt], 16);
        rs[qt] += __shfl_xor(rs[qt], 32);
    }
    // O rows are q = qt*16 + quad*4 + r -> fetch inverse sums via shfl
    float inv[2][4];
    #pragma unroll
    for (int qt = 0; qt < 2; ++qt)
        #pragma unroll
        for (int r = 0; r < 4; ++r)
            inv[qt][r] = 1.0f / __shfl(rs[qt], quad * 4 + r);

    const int b = bh / NHEADS, h = bh % NHEADS;
    #pragma unroll
    for (int qt = 0; qt < 2; ++qt)
        #pragma unroll
        for (int dt = 0; dt < 4; ++dt) {
            const int d = dt * 16 + ln;
            #pragma unroll
            for (int r = 0; r < 4; ++r) {
                const int q = q0 + w * 32 + qt * 16 + quad * 4 + r;
                Og[(size_t)(b * SEQ + q) * CDIM + h * HDIM + d] =
                    (bf16)(o_acc[qt][dt][r] * inv[qt][r]);
            }
        }
}

// ---------------------------------------------------------------------------
extern "C" void kernel_launch(void* const* d_in, const int* in_sizes, int n_in,
                              void* d_out, int out_size, void* d_ws, size_t ws_size,
                              hipStream_t stream)
{
    const float* x     = (const float*)d_in[0];
    const float* Wqkv  = (const float*)d_in[1];
    const float* Wproj = (const float*)d_in[2];
    const float* bproj = (const float*)d_in[3];
    float* out = (float*)d_out;

    bf16* ws   = (bf16*)d_ws;
    bf16* xb   = ws;                                   // [8192][768]
    bf16* wqt  = xb  + PERPART;                        // [2304][768]
    bf16* wpt  = wqt + (size_t)3 * CDIM * CDIM;        // [768][768]
    bf16* q    = wpt + (size_t)CDIM * CDIM;            // [bh][2048][64]
    bf16* k    = q   + PERPART;                        // scaled by log2e/8
    bf16* vt   = k   + PERPART;                        // [bh][64][2048]
    bf16* ao   = vt  + PERPART;                        // [8192][768]

    convert_bf16<<<dim3(PERPART / (256 * 8)), 256, 0, stream>>>(x, xb);
    transpose_convert<<<dim3(3 * CDIM / 64, CDIM / 64), 256, 0, stream>>>(
        Wqkv, wqt, CDIM, 3 * CDIM);
    transpose_convert<<<dim3(CDIM / 64, CDIM / 64), 256, 0, stream>>>(
        Wproj, wpt, CDIM, CDIM);

    gemm128<3 * CDIM, 0><<<dim3(MTOK / 128, 3 * CDIM / 128), 256, 0, stream>>>(
        xb, wqt, nullptr, q, k, vt, nullptr);
    attn_kernel<<<dim3(SEQ / 128, BATCH * NHEADS), 256, 0, stream>>>(q, k, vt, ao);
    gemm128<CDIM, 1><<<dim3(MTOK / 128, CDIM / 128), 256, 0, stream>>>(
        ao, wpt, bproj, nullptr, nullptr, nullptr, out);
}

// Round 10
// 230.234 us; speedup vs baseline: 1.6295x; 1.0558x over previous
//
#include <hip/hip_runtime.h>
#include <math.h>

typedef __bf16 bf16;
typedef __attribute__((ext_vector_type(8))) __bf16 bf16x8;
typedef __attribute__((ext_vector_type(4))) __bf16 bf16x4;
typedef __attribute__((ext_vector_type(4))) float f32x4;

#define NHEADS 12
#define HDIM 64
#define BATCH 4
#define SEQ 2048
#define CDIM 768
#define MTOK (BATCH * SEQ)                    // 8192 tokens
#define PERPART ((size_t)MTOK * CDIM)         // 6291456 elems
#define NBH (BATCH * NHEADS)                  // 48
#define NKBH (SEQ / 2 / 64)                   // 16 key blocks per split half

// K pre-scale: log2(e)/8 -> softmax exp becomes a single 2^x
#define KSCALE 0.18033688011112042f
// constant shift inside exp2 (cancels exactly in normalization)
#define SHIFT 11.54156032f

// async 16B global->LDS DMA (gfx950). lds ptr wave-uniform; HW adds lane*16.
// One wave-instruction covers 64 granules = 1024 B = 512 bf16 elements.
__device__ static inline void load_lds_16(const void* g, void* l)
{
    __builtin_amdgcn_global_load_lds(
        (const __attribute__((address_space(1))) unsigned int*)g,
        (__attribute__((address_space(3))) unsigned int*)l, 16, 0, 0);
}

// ---------------------------------------------------------------------------
// convert fp32 -> bf16, 8 elems/thread
// ---------------------------------------------------------------------------
__global__ __launch_bounds__(256)
void convert_bf16(const float* __restrict__ in, bf16* __restrict__ out)
{
    const size_t i = ((size_t)blockIdx.x * 256 + threadIdx.x) * 8;
    const float4 v0 = *(const float4*)(in + i);
    const float4 v1 = *(const float4*)(in + i + 4);
    alignas(16) bf16 o[8];
    o[0] = (bf16)v0.x; o[1] = (bf16)v0.y; o[2] = (bf16)v0.z; o[3] = (bf16)v0.w;
    o[4] = (bf16)v1.x; o[5] = (bf16)v1.y; o[6] = (bf16)v1.z; o[7] = (bf16)v1.w;
    *(uint4*)(out + i) = *(const uint4*)o;
}

// ---------------------------------------------------------------------------
// transpose+convert: in fp32 [R][C] -> out bf16 [C][R]; 64x64 tiles
// ---------------------------------------------------------------------------
__global__ __launch_bounds__(256)
void transpose_convert(const float* __restrict__ in, bf16* __restrict__ out,
                       int R, int C)
{
    __shared__ bf16 T[64][65];
    const int r0 = blockIdx.y * 64, c0 = blockIdx.x * 64;
    const int t = threadIdx.x;
    const int ir = t >> 2, ic = (t & 3) * 16;
    #pragma unroll
    for (int e = 0; e < 16; ++e)
        T[ir][ic + e] = (bf16)in[(size_t)(r0 + ir) * C + c0 + ic + e];
    __syncthreads();
    const int oc = t >> 2, orr = (t & 3) * 16;
    alignas(16) bf16 tmp[16];
    #pragma unroll
    for (int e = 0; e < 16; ++e)
        tmp[e] = T[orr + e][oc];
    bf16* dst = out + (size_t)(c0 + oc) * R + r0 + orr;
    *(uint4*)dst       = *(const uint4*)tmp;
    *(uint4*)(dst + 8) = *(const uint4*)(tmp + 8);
}

// ---------------------------------------------------------------------------
// m97-style GEMM (unchanged): C[M x NCOLS] = A[M x 768] @ Bt^T. 128x128 tile,
// BK=32, 4 waves (2x2). MODE 0: QKV epilogue -> q, k(*log2e/8), vT bf16.
// MODE 1: proj epilogue -> + bias, fp32 out.
// ---------------------------------------------------------------------------
template<int NCOLS, int MODE>
__global__ __launch_bounds__(256)
void gemm128(const bf16* __restrict__ A, const bf16* __restrict__ Bt,
             const float* __restrict__ bias,
             bf16* __restrict__ qb, bf16* __restrict__ kb, bf16* __restrict__ vtb,
             float* __restrict__ outf)
{
    __shared__ bf16 As[128 * 32];
    __shared__ bf16 Bs[128 * 32];

    const int t    = threadIdx.x;
    const int w    = t >> 6, lane = t & 63;
    const int ln   = lane & 15, quad = lane >> 4;
    const int wr   = w >> 1, wc = w & 1;
    const int m0   = blockIdx.x * 128, n0 = blockIdx.y * 128;

    f32x4 acc[4][4] = {};

    for (int k0 = 0; k0 < CDIM; k0 += 32) {
        #pragma unroll
        for (int i = 0; i < 2; ++i) {
            const int S   = (w * 2 + i) * 64 + lane;     // 16B slot id
            const int row = S >> 2, st = S & 3;
            const int g   = st ^ (row & 3);
            load_lds_16(A  + (size_t)(m0 + row) * CDIM + k0 + g * 8,
                        &As[(w * 2 + i) * 512]);
            load_lds_16(Bt + (size_t)(n0 + row) * CDIM + k0 + g * 8,
                        &Bs[(w * 2 + i) * 512]);
        }
        __syncthreads();

        bf16x8 af[4], bf_[4];
        #pragma unroll
        for (int mt = 0; mt < 4; ++mt) {
            const int row = wr * 64 + mt * 16 + ln;
            af[mt] = *(const bf16x8*)&As[row * 32 + (quad ^ (row & 3)) * 8];
        }
        #pragma unroll
        for (int nt = 0; nt < 4; ++nt) {
            const int row = wc * 64 + nt * 16 + ln;
            bf_[nt] = *(const bf16x8*)&Bs[row * 32 + (quad ^ (row & 3)) * 8];
        }
        #pragma unroll
        for (int mt = 0; mt < 4; ++mt)
            #pragma unroll
            for (int nt = 0; nt < 4; ++nt)
                acc[mt][nt] = __builtin_amdgcn_mfma_f32_16x16x32_bf16(
                    af[mt], bf_[nt], acc[mt][nt], 0, 0, 0);
        __syncthreads();
    }

    #pragma unroll
    for (int nt = 0; nt < 4; ++nt) {
        const int c = n0 + wc * 64 + nt * 16 + ln;
        if constexpr (MODE == 0) {
            const int p = c / CDIM, rem = c - p * CDIM;
            const int h = rem >> 6, d = rem & 63;
            #pragma unroll
            for (int mt = 0; mt < 4; ++mt) {
                const int row0 = m0 + wr * 64 + mt * 16 + quad * 4;
                const int b = row0 >> 11, nn = row0 & 2047;
                if (p == 0) {
                    bf16* dst = qb + ((size_t)(b * NHEADS + h) * SEQ + nn) * HDIM + d;
                    #pragma unroll
                    for (int r = 0; r < 4; ++r) dst[r * HDIM] = (bf16)acc[mt][nt][r];
                } else if (p == 1) {
                    bf16* dst = kb + ((size_t)(b * NHEADS + h) * SEQ + nn) * HDIM + d;
                    #pragma unroll
                    for (int r = 0; r < 4; ++r) dst[r * HDIM] = (bf16)(acc[mt][nt][r] * KSCALE);
                } else {
                    alignas(8) bf16 pk[4];
                    #pragma unroll
                    for (int r = 0; r < 4; ++r) pk[r] = (bf16)acc[mt][nt][r];
                    *(uint2*)(vtb + ((size_t)(b * NHEADS + h) * HDIM + d) * SEQ + nn) =
                        *(const uint2*)pk;
                }
            }
        } else {
            const float bv = bias[c];
            #pragma unroll
            for (int mt = 0; mt < 4; ++mt) {
                const int row0 = m0 + wr * 64 + mt * 16 + quad * 4;
                #pragma unroll
                for (int r = 0; r < 4; ++r)
                    outf[(size_t)(row0 + r) * CDIM + c] = acc[mt][nt][r] + bv;
            }
        }
    }
}

// ---------------------------------------------------------------------------
// Flash attention v5: 2-way key split (blockIdx.z), Q frags direct from
// global (no Qs LDS -> 32KB LDS), double-buffered K/V prefetch, PV via
// 16x16x32, row-sums via all-ones-B MFMA (racc lands in C-layout -> no
// shuffles). Writes UNNORMALIZED bf16 O-partials + f32 rs-partials; a
// combine kernel merges the two halves. grid (SEQ/128, NBH, 2).
// ---------------------------------------------------------------------------
__global__ __launch_bounds__(256, 4)
void attn_kernel(const bf16* __restrict__ Qg, const bf16* __restrict__ Kg,
                 const bf16* __restrict__ Vtg,
                 bf16* __restrict__ Op, float* __restrict__ rsp)
{
    __shared__ bf16 Ks[2][64 * 64];        // [key][d], double-buffered
    __shared__ bf16 Vs[2][64 * 64];        // [d][key], double-buffered

    const int t    = threadIdx.x;
    const int w    = t >> 6, lane = t & 63;
    const int ln   = lane & 15, quad = lane >> 4;
    const int bh   = blockIdx.y, q0 = blockIdx.x * 128;
    const int z    = blockIdx.z;
    const int kbase = z * (SEQ / 2);       // first key of this half

    const bf16* Qb = Qg  + (size_t)bh * SEQ * HDIM;
    const bf16* Kb = Kg  + (size_t)bh * SEQ * HDIM;
    const bf16* Vb = Vtg + (size_t)bh * HDIM * SEQ;

    // Q fragments straight from global (16B aligned, one-time)
    bf16x8 qf[2][2];
    #pragma unroll
    for (int qt = 0; qt < 2; ++qt)
        #pragma unroll
        for (int kk = 0; kk < 2; ++kk) {
            const int row = w * 32 + qt * 16 + ln;
            qf[qt][kk] = *(const bf16x8*)(Qb + (size_t)(q0 + row) * HDIM
                                          + (kk * 4 + quad) * 8);
        }

    // stage K/V block 0 of this half into buf 0
    #pragma unroll
    for (int i = 0; i < 2; ++i) {
        const int S = w * 128 + i * 64 + lane;
        const int row = S >> 3, g = (S & 7) ^ (row & 7);
        load_lds_16(Kb + (size_t)(kbase + row) * HDIM + g * 8, &Ks[0][(w * 2 + i) * 512]);
        load_lds_16(Vb + (size_t)row * SEQ + kbase + g * 8,    &Vs[0][(w * 2 + i) * 512]);
    }
    __syncthreads();

    bf16x8 ones;
    #pragma unroll
    for (int e = 0; e < 8; ++e) ones[e] = (bf16)1.0f;

    f32x4 o_acc[2][4] = {};
    f32x4 racc[2] = {};                    // row sums, C-layout rows = quad*4+r

    for (int kb = 0; kb < NKBH; ++kb) {
        // prefetch next K/V block (drains at barrier below, overlapped)
        if (kb + 1 < NKBH) {
            const int nb = (kb + 1) & 1;
            #pragma unroll
            for (int i = 0; i < 2; ++i) {
                const int S = w * 128 + i * 64 + lane;
                const int row = S >> 3, g = (S & 7) ^ (row & 7);
                load_lds_16(Kb + (size_t)(kbase + (kb + 1) * 64 + row) * HDIM + g * 8,
                            &Ks[nb][(w * 2 + i) * 512]);
                load_lds_16(Vb + (size_t)row * SEQ + kbase + (kb + 1) * 64 + g * 8,
                            &Vs[nb][(w * 2 + i) * 512]);
            }
        }

        const bf16* Ksb = Ks[kb & 1];
        const bf16* Vsb = Vs[kb & 1];

        #pragma unroll
        for (int p = 0; p < 2; ++p) {          // pair of 16-key tiles
            union { bf16x8 v8; bf16x4 v4[2]; } pf8[2];
            #pragma unroll
            for (int sub = 0; sub < 2; ++sub) {
                const int mt = p * 2 + sub;
                bf16x8 ka[2];
                #pragma unroll
                for (int kk = 0; kk < 2; ++kk) {
                    const int row = mt * 16 + ln;
                    const int g = (kk * 4 + quad) ^ (row & 7);
                    ka[kk] = *(const bf16x8*)&Ksb[row * 64 + g * 8];
                }
                #pragma unroll
                for (int qt = 0; qt < 2; ++qt) {
                    f32x4 a = {-SHIFT, -SHIFT, -SHIFT, -SHIFT};
                    a = __builtin_amdgcn_mfma_f32_16x16x32_bf16(ka[0], qf[qt][0], a, 0, 0, 0);
                    a = __builtin_amdgcn_mfma_f32_16x16x32_bf16(ka[1], qf[qt][1], a, 0, 0, 0);
                    bf16x4 pb = { (bf16)exp2f(a[0]), (bf16)exp2f(a[1]),
                                  (bf16)exp2f(a[2]), (bf16)exp2f(a[3]) };
                    pf8[qt].v4[sub] = pb;
                }
            }
            // row sums on the MFMA pipe: B = all-ones
            #pragma unroll
            for (int qt = 0; qt < 2; ++qt)
                racc[qt] = __builtin_amdgcn_mfma_f32_16x16x32_bf16(
                    pf8[qt].v8, ones, racc[qt], 0, 0, 0);
            // O += P(32 keys) * V via 16x16x32
            #pragma unroll
            for (int dt = 0; dt < 4; ++dt) {
                const int row = dt * 16 + ln;               // d
                union { bf16x8 v8; bf16x4 v4[2]; } vv;
                #pragma unroll
                for (int sub = 0; sub < 2; ++sub) {
                    const int G = (p * 2 + sub) * 2 + (quad >> 1);
                    const int g = G ^ (row & 7);
                    vv.v4[sub] = *(const bf16x4*)&Vsb[row * 64 + g * 8 + (quad & 1) * 4];
                }
                #pragma unroll
                for (int qt = 0; qt < 2; ++qt)
                    o_acc[qt][dt] = __builtin_amdgcn_mfma_f32_16x16x32_bf16(
                        pf8[qt].v8, vv.v8, o_acc[qt][dt], 0, 0, 0);
            }
        }
        __syncthreads();   // drains prefetch (overlapped) + guards buffer swap
    }

    // epilogue: unnormalized partials. Op layout [z*NBH+bh][q][d]
    bf16* Ob = Op + (size_t)(z * NBH + bh) * SEQ * HDIM;
    #pragma unroll
    for (int qt = 0; qt < 2; ++qt)
        #pragma unroll
        for (int dt = 0; dt < 4; ++dt) {
            const int d = dt * 16 + ln;
            #pragma unroll
            for (int r = 0; r < 4; ++r) {
                const int q = q0 + w * 32 + qt * 16 + quad * 4 + r;
                Ob[(size_t)q * HDIM + d] = (bf16)o_acc[qt][dt][r];
            }
        }
    if (ln == 0) {
        float* rb = rsp + (size_t)(z * NBH + bh) * SEQ;
        #pragma unroll
        for (int qt = 0; qt < 2; ++qt)
            #pragma unroll
            for (int r = 0; r < 4; ++r)
                rb[q0 + w * 32 + qt * 16 + quad * 4 + r] = racc[qt][r];
    }
}

// ---------------------------------------------------------------------------
// combine: ao[b, q, h*64+d] = (O0 + O1) / (rs0 + rs1). grid (SEQ/32, NBH).
// ---------------------------------------------------------------------------
__global__ __launch_bounds__(256)
void attn_combine(const bf16* __restrict__ Op, const float* __restrict__ rsp,
                  bf16* __restrict__ ao)
{
    const int t  = threadIdx.x;
    const int bh = blockIdx.y;
    const int q  = blockIdx.x * 32 + (t >> 3);
    const int d0 = (t & 7) * 8;

    const float inv = 1.0f / (rsp[(size_t)bh * SEQ + q] +
                              rsp[(size_t)(NBH + bh) * SEQ + q]);
    const bf16x8 a = *(const bf16x8*)(Op + ((size_t)bh * SEQ + q) * HDIM + d0);
    const bf16x8 b = *(const bf16x8*)(Op + ((size_t)(NBH + bh) * SEQ + q) * HDIM + d0);

    const int bb = bh / NHEADS, h = bh % NHEADS;
    alignas(16) bf16 o[8];
    #pragma unroll
    for (int e = 0; e < 8; ++e)
        o[e] = (bf16)(((float)a[e] + (float)b[e]) * inv);
    *(uint4*)(ao + (size_t)(bb * SEQ + q) * CDIM + h * HDIM + d0) = *(const uint4*)o;
}

// ---------------------------------------------------------------------------
extern "C" void kernel_launch(void* const* d_in, const int* in_sizes, int n_in,
                              void* d_out, int out_size, void* d_ws, size_t ws_size,
                              hipStream_t stream)
{
    const float* x     = (const float*)d_in[0];
    const float* Wqkv  = (const float*)d_in[1];
    const float* Wproj = (const float*)d_in[2];
    const float* bproj = (const float*)d_in[3];
    float* out = (float*)d_out;

    bf16* ws   = (bf16*)d_ws;
    bf16* xb   = ws;                                   // [8192][768]
    bf16* wqt  = xb  + PERPART;                        // [2304][768]
    bf16* wpt  = wqt + (size_t)3 * CDIM * CDIM;        // [768][768]
    bf16* q    = wpt + (size_t)CDIM * CDIM;            // [bh][2048][64]
    bf16* k    = q   + PERPART;                        // scaled by log2e/8
    bf16* vt   = k   + PERPART;                        // [bh][64][2048]
    bf16* ao   = vt  + PERPART;                        // [8192][768]
    bf16* op   = ao  + PERPART;                        // [2*48][2048][64] partials
    float* rsp = (float*)(op + (size_t)2 * NBH * SEQ * HDIM);  // [2*48][2048]

    convert_bf16<<<dim3(PERPART / (256 * 8)), 256, 0, stream>>>(x, xb);
    transpose_convert<<<dim3(3 * CDIM / 64, CDIM / 64), 256, 0, stream>>>(
        Wqkv, wqt, CDIM, 3 * CDIM);
    transpose_convert<<<dim3(CDIM / 64, CDIM / 64), 256, 0, stream>>>(
        Wproj, wpt, CDIM, CDIM);

    gemm128<3 * CDIM, 0><<<dim3(MTOK / 128, 3 * CDIM / 128), 256, 0, stream>>>(
        xb, wqt, nullptr, q, k, vt, nullptr);
    attn_kernel<<<dim3(SEQ / 128, NBH, 2), 256, 0, stream>>>(q, k, vt, op, rsp);
    attn_combine<<<dim3(SEQ / 32, NBH), 256, 0, stream>>>(op, rsp, ao);
    gemm128<CDIM, 1><<<dim3(MTOK / 128, CDIM / 128), 256, 0, stream>>>(
        ao, wpt, bproj, nullptr, nullptr, nullptr, out);
}